// Round 1
// baseline (30.677 us; speedup 1.0000x reference)
//
#include <hip/hip_runtime.h>
#include <math.h>

#define SEQ_L 4096
#define NBATCH 4
#define BLOCKS_PER_BATCH 512   // 4 waves/block * 512 = 2048 waves/batch = L/2 row-pairs

__global__ __launch_bounds__(256) void attn_rows_kernel(
    const float* __restrict__ x,
    const float* __restrict__ q_weight,
    const float* __restrict__ v_weight,
    const float* __restrict__ gate_weight,
    const float* __restrict__ carry_weight,
    float* __restrict__ out,
    float scale, float omega)
{
    // exactly 32768 B -> 5 blocks/CU LDS-limited
    __shared__ float2 aw[SEQ_L];

    const int tid  = threadIdx.x;
    const int lane = tid & 63;
    const int wave = tid >> 6;
    const int b    = blockIdx.x / BLOCKS_PER_BATCH;
    const int bb   = blockIdx.x % BLOCKS_PER_BATCH;

    const float phi = q_weight[0];
    const float vw  = v_weight[0];

    const float2* x2 = (const float2*)x + (size_t)b * SEQ_L;

    // Phase 0: stage a_j, w_j for the whole batch row into LDS
    for (int j = tid; j < SEQ_L; j += 256) {
        float2 xv = x2[j];
        float inv = rsqrtf((xv.x * xv.x + xv.y * xv.y) * 0.5f + 1e-6f);
        float xn0 = xv.x * inv;
        float xn1 = xv.y * inv;
        float a = xn0 * rsqrtf(xn0 * xn0 * 0.5f + 1e-6f);   // |a| < sqrt(2)
        float w = xn1 * vw;
        aw[j] = make_float2(a, w);
    }

    // cos table in registers: lane d (d<19) holds c_d = cos(omega*d - phi)
    float creg = cosf(omega * (float)(lane < 19 ? lane : 0) - phi);

    __syncthreads();

    const float ga = gate_weight[0];
    const float gc = gate_weight[1];
    const float cw = carry_weight[0];

    const int v = bb * 4 + wave;              // 0..2047
    const float LOG2E = 1.4426950408889634f;
    const float SQRT2 = 1.4142135623730951f;

    #pragma unroll
    for (int rr = 0; rr < 2; ++rr) {
        const int i = (rr == 0) ? v : (SEQ_L - 1 - v);

        const float a_i = aw[i].x;            // broadcast
        const float t2  = scale * a_i * LOG2E;
        const float M2  = fabsf(t2) * SQRT2;  // static per-row max bound (log2 domain)

        float s = 0.f, o = 0.f;

        int d = (i - lane) % 19;              // truncated mod; fix sign
        if (d < 0) d += 19;

        for (int j = lane; j <= i; j += 64) {
            float2 p = aw[j];
            float  c = __shfl(creg, d);
            float  e = exp2f(fmaf(t2, p.x * c, -M2));   // always <= ~1
            s += e;
            o  = fmaf(e, p.y, o);
            d -= 7;                            // (i-j) drops by 64 == 7 (mod 19)
            if (d < 0) d += 19;
        }

        // wave reduction of (s, o)
        for (int off = 32; off > 0; off >>= 1) {
            s += __shfl_xor(s, off);
            o += __shfl_xor(o, off);
        }

        if (lane == 0) {
            float o0 = o / s;
            float2 xv = x2[i];
            float h0 = xv.x;
            float h1 = xv.y + o0;
            float inv = rsqrtf((h0 * h0 + h1 * h1) * 0.5f + 1e-6f);
            float hn0 = h0 * inv, hn1 = h1 * inv;
            float g0 = hn0 * ga + hn1 * gc;
            float g1 = hn0 * (ga - gc * 1e-3f) + hn1 * gc;
            float sig0 = 1.f / (1.f + expf(-g0));
            float sig1 = 1.f / (1.f + expf(-g1));
            float mix0 = g0 * sig0 * hn0;      // silu(g0) * base, base = hn0
            float mix1 = g1 * sig1 * hn0;      // silu(g1) * base  (same base!)
            float y1 = cw * (mix1 - mix0);
            float2* outp = (float2*)out + (size_t)b * SEQ_L + i;
            *outp = make_float2(xv.x, h1 + y1);
        }
    }
}

extern "C" void kernel_launch(void* const* d_in, const int* in_sizes, int n_in,
                              void* d_out, int out_size, void* d_ws, size_t ws_size,
                              hipStream_t stream)
{
    const float* x  = (const float*)d_in[0];
    // d_in[1] = mask (1,1,L,L) — causality handled analytically, unused
    const float* qw = (const float*)d_in[2];
    const float* vw = (const float*)d_in[3];
    const float* gw = (const float*)d_in[4];
    const float* cw = (const float*)d_in[5];
    float* out = (float*)d_out;

    const double omega = 2.0 * M_PI / 19.0;
    const double amp   = log(10.0) / (cos(omega * 0.3) - cos(omega * 0.7));
    const double qkns2 = amp / sqrt(2.0);               // QK_NORM_SCALE^2
    const double scale = pow(2.0, -0.5) * qkns2;        // HEAD_DIM^-0.5 * QK_NORM_SCALE^2

    attn_rows_kernel<<<dim3(NBATCH * BLOCKS_PER_BATCH), dim3(256), 0, stream>>>(
        x, qw, vw, gw, cw, out, (float)scale, (float)omega);
}

// Round 2
// 25.237 us; speedup vs baseline: 1.2155x; 1.2155x over previous
//
#include <hip/hip_runtime.h>
#include <math.h>

#define SEQ_L 4096
#define THREADS 512
#define WAVES 8
#define BLOCKS_PER_BATCH 256   // 256 blocks * 8 waves = 2048 row-pairs per batch

__global__ __launch_bounds__(THREADS) void attn_rows_kernel(
    const float* __restrict__ x,
    const float* __restrict__ q_weight,
    const float* __restrict__ v_weight,
    const float* __restrict__ gate_weight,
    const float* __restrict__ carry_weight,
    float* __restrict__ out,
    float scale, float omega, float cd, float sd)
{
    __shared__ float2 aw[SEQ_L];   // 32 KB -> 4 blocks/CU (waves-capped) = 100% occupancy

    const int tid  = threadIdx.x;
    const int lane = tid & 63;
    const int wave = tid >> 6;
    const int b    = blockIdx.x >> 8;    // / BLOCKS_PER_BATCH
    const int bb   = blockIdx.x & 255;

    const float phi = q_weight[0];
    const float vw  = v_weight[0];
    const float2* x2 = (const float2*)x + (size_t)b * SEQ_L;

    // Phase 0: stage a_j, w_j for the whole batch row into LDS
    for (int j = tid; j < SEQ_L; j += THREADS) {
        float2 xv = x2[j];
        float inv = rsqrtf((xv.x * xv.x + xv.y * xv.y) * 0.5f + 1e-6f);
        float xn0 = xv.x * inv;
        float xn1 = xv.y * inv;
        float a = xn0 * rsqrtf(xn0 * xn0 * 0.5f + 1e-6f);   // |a| < sqrt(2)
        aw[j] = make_float2(a, xn1 * vw);
    }
    __syncthreads();

    const float ga = gate_weight[0];
    const float gc = gate_weight[1];
    const float cw = carry_weight[0];

    const int v = bb * WAVES + wave;     // 0..2047
    const float LOG2E = 1.4426950408889634f;
    const float SQRT2 = 1.4142135623730951f;

    #pragma unroll
    for (int rr = 0; rr < 2; ++rr) {
        const int i = (rr == 0) ? v : (SEQ_L - 1 - v);   // wave-uniform

        const float a_i = aw[i].x;               // same-address broadcast, free
        const float t2  = scale * a_i * LOG2E;
        const float M2  = fabsf(t2) * SQRT2;     // static per-row max bound (log2 domain)

        // initial angle theta = omega*(i-lane) - phi, reduced exactly via period 19
        unsigned r = (unsigned)(i - lane + 76) % 19u;
        float th = omega * (float)r - phi;
        float c = cosf(th);
        float s = sinf(th);

        float ssum = 0.f, osum = 0.f;
        int j = lane;
        const int kfull = i >> 6;                // wave-uniform -> scalar loop

        #pragma unroll 2
        for (int k = 0; k < kfull; ++k) {
            float2 p = aw[j];
            float e = exp2f(fmaf(t2, p.x * c, -M2));   // always <= ~1, never all-zero
            ssum += e;
            osum = fmaf(e, p.y, osum);
            // rotate angle by -delta (delta = 64*omega): cos/sin recurrence
            float cn = fmaf(s, sd, c * cd);
            float sn = fmaf(s, cd, -(c * sd));
            c = cn; s = sn;
            j += 64;
        }
        // final (partial) iteration: j = lane + (kfull<<6) <= 4095 always in-bounds
        {
            float2 p = aw[j];
            float e = exp2f(fmaf(t2, p.x * c, -M2));
            e = (lane <= (i & 63)) ? e : 0.f;
            ssum += e;
            osum = fmaf(e, p.y, osum);
        }

        // wave reduction of (ssum, osum)
        for (int off = 32; off > 0; off >>= 1) {
            ssum += __shfl_xor(ssum, off);
            osum += __shfl_xor(osum, off);
        }

        if (lane == 0) {
            float o0 = osum / ssum;
            float2 xv = x2[i];
            float h0 = xv.x;
            float h1 = xv.y + o0;
            float inv = rsqrtf((h0 * h0 + h1 * h1) * 0.5f + 1e-6f);
            float hn0 = h0 * inv, hn1 = h1 * inv;
            float g0 = hn0 * ga + hn1 * gc;
            float g1 = hn0 * (ga - gc * 1e-3f) + hn1 * gc;
            float sig0 = 1.f / (1.f + expf(-g0));
            float sig1 = 1.f / (1.f + expf(-g1));
            float mix0 = g0 * sig0 * hn0;
            float mix1 = g1 * sig1 * hn0;
            float y1 = cw * (mix1 - mix0);
            float2* outp = (float2*)out + (size_t)b * SEQ_L + i;
            *outp = make_float2(xv.x, h1 + y1);
        }
    }
}

extern "C" void kernel_launch(void* const* d_in, const int* in_sizes, int n_in,
                              void* d_out, int out_size, void* d_ws, size_t ws_size,
                              hipStream_t stream)
{
    const float* x  = (const float*)d_in[0];
    // d_in[1] = mask — causality handled analytically, unused
    const float* qw = (const float*)d_in[2];
    const float* vw = (const float*)d_in[3];
    const float* gw = (const float*)d_in[4];
    const float* cw = (const float*)d_in[5];
    float* out = (float*)d_out;

    const double omega = 2.0 * M_PI / 19.0;
    const double amp   = log(10.0) / (cos(omega * 0.3) - cos(omega * 0.7));
    const double qkns2 = amp / sqrt(2.0);               // QK_NORM_SCALE^2
    const double scale = pow(2.0, -0.5) * qkns2;        // HEAD_DIM^-0.5 * QK_NORM_SCALE^2
    const double delta = 64.0 * omega;                  // per-iteration angle decrement

    attn_rows_kernel<<<dim3(4 * BLOCKS_PER_BATCH), dim3(THREADS), 0, stream>>>(
        x, qw, vw, gw, cw, out,
        (float)scale, (float)omega, (float)cos(delta), (float)sin(delta));
}

// Round 3
// 18.537 us; speedup vs baseline: 1.6549x; 1.3614x over previous
//
#include <hip/hip_runtime.h>
#include <math.h>

#define SEQ_L 4096
#define THREADS 512
#define WAVES 8
#define BLOCKS_PER_BATCH 256   // 256 blocks * 8 waves = 2048 row-pairs per batch

__global__ __launch_bounds__(THREADS) void attn_rows_kernel(
    const float* __restrict__ x,
    const float* __restrict__ q_weight,
    const float* __restrict__ v_weight,
    const float* __restrict__ gate_weight,
    const float* __restrict__ carry_weight,
    float* __restrict__ out,
    float scaleL2,           // SCALE * log2(e)
    float omega,
    float cd, float sd,      // cos(256*omega), sin(256*omega)
    float ck1, float sk1,    // cos(k*omega), sin(k*omega), k=1..3
    float ck2, float sk2,
    float ck3, float sk3)
{
    __shared__ float As[SEQ_L];   // 16 KB
    __shared__ float Ws[SEQ_L];   // 16 KB  (total 32 KB -> 4 blocks/CU)

    const int tid  = threadIdx.x;
    const int lane = tid & 63;
    const int wave = tid >> 6;
    const int b    = blockIdx.x >> 8;    // / BLOCKS_PER_BATCH
    const int bb   = blockIdx.x & 255;

    const float phi = q_weight[0];
    const float vw  = v_weight[0];
    const float2* x2 = (const float2*)x + (size_t)b * SEQ_L;

    // Phase 0: stage a_j (attn amplitude) and w_j (value) into LDS, fp32
    for (int j = tid; j < SEQ_L; j += THREADS) {
        float2 xv = x2[j];
        float inv = rsqrtf((xv.x * xv.x + xv.y * xv.y) * 0.5f + 1e-6f);
        float xn0 = xv.x * inv;
        float xn1 = xv.y * inv;
        As[j] = xn0 * rsqrtf(xn0 * xn0 * 0.5f + 1e-6f);   // |a| < sqrt(2)
        Ws[j] = xn1 * vw;
    }
    __syncthreads();

    const float ga = gate_weight[0];
    const float gc = gate_weight[1];
    const float cw = carry_weight[0];

    const int v = bb * WAVES + wave;     // 0..2047
    const float SQRT2 = 1.4142135623730951f;
    const float LOG2E = 1.4426950408889634f;

    #pragma unroll
    for (int rr = 0; rr < 2; ++rr) {
        const int i = (rr == 0) ? v : (SEQ_L - 1 - v);   // wave-uniform

        const float t2 = scaleL2 * As[i];        // same-address broadcast read
        const float M2 = fabsf(t2) * SQRT2;      // static per-row max bound (log2 units)

        // base angle for this lane's first element (j = 4*lane):
        // theta = omega*((i - 4*lane) mod 19) - phi   (266 = 14*19)
        unsigned r = (unsigned)(i - (lane << 2) + 266) % 19u;
        float th = omega * (float)r - phi;
        float C = t2 * cosf(th);                 // t2 folded into rotation state
        float S = t2 * sinf(th);

        float ssum = 0.f, osum = 0.f;
        int jb = lane << 2;                      // element index, this lane
        const int nfull = (i + 1) >> 8;          // wave-uniform full iterations

        for (int k = 0; k < nfull; ++k) {
            float4 av = *(const float4*)&As[jb];     // ds_read_b128
            float4 wv = *(const float4*)&Ws[jb];     // ds_read_b128
            float C1 = fmaf(S, sk1, C * ck1);
            float C2 = fmaf(S, sk2, C * ck2);
            float C3 = fmaf(S, sk3, C * ck3);
            float e0 = __builtin_amdgcn_exp2f(fmaf(av.x, C,  -M2));
            float e1 = __builtin_amdgcn_exp2f(fmaf(av.y, C1, -M2));
            float e2 = __builtin_amdgcn_exp2f(fmaf(av.z, C2, -M2));
            float e3 = __builtin_amdgcn_exp2f(fmaf(av.w, C3, -M2));
            ssum += (e0 + e1) + (e2 + e3);
            osum = fmaf(e0, wv.x, osum);
            osum = fmaf(e1, wv.y, osum);
            osum = fmaf(e2, wv.z, osum);
            osum = fmaf(e3, wv.w, osum);
            // rotate base angle by -256*omega
            float Cn = fmaf(S, sd, C * cd);
            float Sn = fmaf(S, cd, -(C * sd));
            C = Cn; S = Sn;
            jb += 256;
        }
        // unconditional masked tail (reads stay inside the 32 KB LDS block;
        // invalid elements are zeroed after exp)
        {
            float4 av = *(const float4*)&As[jb];
            float4 wv = *(const float4*)&Ws[jb];
            float C1 = fmaf(S, sk1, C * ck1);
            float C2 = fmaf(S, sk2, C * ck2);
            float C3 = fmaf(S, sk3, C * ck3);
            float e0 = __builtin_amdgcn_exp2f(fmaf(av.x, C,  -M2));
            float e1 = __builtin_amdgcn_exp2f(fmaf(av.y, C1, -M2));
            float e2 = __builtin_amdgcn_exp2f(fmaf(av.z, C2, -M2));
            float e3 = __builtin_amdgcn_exp2f(fmaf(av.w, C3, -M2));
            e0 = (jb + 0 <= i) ? e0 : 0.f;
            e1 = (jb + 1 <= i) ? e1 : 0.f;
            e2 = (jb + 2 <= i) ? e2 : 0.f;
            e3 = (jb + 3 <= i) ? e3 : 0.f;
            ssum += (e0 + e1) + (e2 + e3);
            osum = fmaf(e0, wv.x, osum);
            osum = fmaf(e1, wv.y, osum);
            osum = fmaf(e2, wv.z, osum);
            osum = fmaf(e3, wv.w, osum);
        }

        // wave reduction of (ssum, osum)
        for (int off = 32; off > 0; off >>= 1) {
            ssum += __shfl_xor(ssum, off);
            osum += __shfl_xor(osum, off);
        }

        if (lane == 0) {
            float o0 = osum * __builtin_amdgcn_rcpf(ssum);
            float2 xv = x2[i];
            float h0 = xv.x;
            float h1 = xv.y + o0;
            float inv = __builtin_amdgcn_rsqf(
                           fmaf(h0, h0 * 0.5f, fmaf(h1, h1 * 0.5f, 1e-6f)));
            float hn0 = h0 * inv, hn1 = h1 * inv;
            float g0 = hn0 * ga + hn1 * gc;
            float g1 = hn0 * (ga - gc * 1e-3f) + hn1 * gc;
            float sig0 = __builtin_amdgcn_rcpf(1.f + __builtin_amdgcn_exp2f(-g0 * LOG2E));
            float sig1 = __builtin_amdgcn_rcpf(1.f + __builtin_amdgcn_exp2f(-g1 * LOG2E));
            float mix0 = g0 * sig0 * hn0;
            float mix1 = g1 * sig1 * hn0;
            float y1 = cw * (mix1 - mix0);
            float2* outp = (float2*)out + (size_t)b * SEQ_L + i;
            *outp = make_float2(xv.x, h1 + y1);
        }
    }
}

extern "C" void kernel_launch(void* const* d_in, const int* in_sizes, int n_in,
                              void* d_out, int out_size, void* d_ws, size_t ws_size,
                              hipStream_t stream)
{
    const float* x  = (const float*)d_in[0];
    // d_in[1] = mask — causality handled analytically, unused
    const float* qw = (const float*)d_in[2];
    const float* vw = (const float*)d_in[3];
    const float* gw = (const float*)d_in[4];
    const float* cw = (const float*)d_in[5];
    float* out = (float*)d_out;

    const double omega = 2.0 * M_PI / 19.0;
    const double amp   = log(10.0) / (cos(omega * 0.3) - cos(omega * 0.7));
    const double qkns2 = amp / sqrt(2.0);               // QK_NORM_SCALE^2
    const double scale = pow(2.0, -0.5) * qkns2;        // HEAD_DIM^-0.5 * QK_NORM_SCALE^2
    const double L2E   = 1.4426950408889634074;
    const double delta = 256.0 * omega;                 // per-iteration angle decrement

    attn_rows_kernel<<<dim3(4 * BLOCKS_PER_BATCH), dim3(THREADS), 0, stream>>>(
        x, qw, vw, gw, cw, out,
        (float)(scale * L2E), (float)omega,
        (float)cos(delta),       (float)sin(delta),
        (float)cos(omega),       (float)sin(omega),
        (float)cos(2.0 * omega), (float)sin(2.0 * omega),
        (float)cos(3.0 * omega), (float)sin(3.0 * omega));
}